// Round 1
// baseline (617.306 us; speedup 1.0000x reference)
//
#include <hip/hip_runtime.h>

#define N_ATOMS 10000
#define N_PAIRS 500000
#define N_DESC  64

// ---------------------------------------------------------------------------
// Kernel 0: initialize output. d_out[0] = b_last (energy bias), rest = 0.
// Harness re-poisons d_out to 0xAA before every timed launch, so we must
// zero it ourselves before the atomic accumulation kernels.
// ---------------------------------------------------------------------------
__global__ void init_out_kernel(float* __restrict__ out,
                                const float* __restrict__ b_last,
                                int out_size) {
    int i = blockIdx.x * blockDim.x + threadIdx.x;
    if (i < out_size) out[i] = (i == 0) ? b_last[0] : 0.0f;
}

// ---------------------------------------------------------------------------
// Kernel A: per-atom table + energy reduction.
//   e  = tanh(coeffs[n][d] * w1[d] + b1[d])
//   g[n][d] = (1 - e*e) * w1[d] * w_last[d]      (stored to workspace)
//   energy += e * w_last[d] / N_ATOMS            (atomic into out[0])
// One thread per (n,d) element; 640K elements total.
// ---------------------------------------------------------------------------
__global__ void atom_kernel(const float* __restrict__ coeffs,
                            const float* __restrict__ w1,
                            const float* __restrict__ b1,
                            const float* __restrict__ w_last,
                            float* __restrict__ g,
                            float* __restrict__ out) {
    const int i = blockIdx.x * blockDim.x + threadIdx.x;   // < N_ATOMS*N_DESC
    const int d = i & (N_DESC - 1);

    const float wd = w1[d];
    const float wl = w_last[d];
    const float e  = tanhf(coeffs[i] * wd + b1[d]);

    g[i] = (1.0f - e * e) * wd * wl;

    float epart = e * wl * (1.0f / (float)N_ATOMS);

    // 64-lane wave reduction
    #pragma unroll
    for (int off = 32; off > 0; off >>= 1)
        epart += __shfl_down(epart, off, 64);

    __shared__ float smem[4];                 // 256 threads = 4 waves
    const int lane = threadIdx.x & 63;
    const int wv   = threadIdx.x >> 6;
    if (lane == 0) smem[wv] = epart;
    __syncthreads();
    if (threadIdx.x == 0) {
        atomicAdd(out, smem[0] + smem[1] + smem[2] + smem[3]);
    }
}

// ---------------------------------------------------------------------------
// Kernel B: one wave (64 lanes) per pair. Lane d owns descriptor d.
//   s_k = sum_d g[central[p]][d] * cd[k][p][d]      (k = 0,1,2)
//   out_f[k][neigh[p]] += -s_k
// All global loads are lane-coalesced 256B rows. g gather hits L2 (2.56MB).
// ---------------------------------------------------------------------------
__global__ void pair_kernel(const float* __restrict__ cd,      // [3, P, 64]
                            const float* __restrict__ g,       // [N, 64]
                            const int*   __restrict__ central, // [P]
                            const int*   __restrict__ neigh,   // [P]
                            float* __restrict__ out_f) {       // [3, N] (= d_out+1)
    const int wave = (blockIdx.x * blockDim.x + threadIdx.x) >> 6;
    const int lane = threadIdx.x & 63;
    if (wave >= N_PAIRS) return;

    const int c = central[wave];               // wave-uniform -> scalar load
    const float gv = g[c * N_DESC + lane];

    const size_t plane = (size_t)N_PAIRS * N_DESC;
    const float* base = cd + (size_t)wave * N_DESC + lane;
    float s0 = gv * base[0];
    float s1 = gv * base[plane];
    float s2 = gv * base[2 * plane];

    #pragma unroll
    for (int off = 32; off > 0; off >>= 1) {
        s0 += __shfl_down(s0, off, 64);
        s1 += __shfl_down(s1, off, 64);
        s2 += __shfl_down(s2, off, 64);
    }

    if (lane == 0) {
        const int nb = neigh[wave];
        atomicAdd(&out_f[nb],               -s0);
        atomicAdd(&out_f[N_ATOMS + nb],     -s1);
        atomicAdd(&out_f[2 * N_ATOMS + nb], -s2);
    }
}

// ---------------------------------------------------------------------------
// Launch
// ---------------------------------------------------------------------------
extern "C" void kernel_launch(void* const* d_in, const int* in_sizes, int n_in,
                              void* d_out, int out_size, void* d_ws, size_t ws_size,
                              hipStream_t stream) {
    const float* coeffs  = (const float*)d_in[0];   // [1, N, 64]
    const float* cd      = (const float*)d_in[1];   // [1, 3, P, 64]
    const float* w1      = (const float*)d_in[2];   // [64]
    const float* b1      = (const float*)d_in[3];   // [64]
    const float* w_last  = (const float*)d_in[4];   // [64]
    const float* b_last  = (const float*)d_in[5];   // [1]
    const int*   central = (const int*)d_in[6];     // [P]
    const int*   neigh   = (const int*)d_in[7];     // [P]

    float* out   = (float*)d_out;                   // [0]=energy, [1..30000]=forces
    float* g     = (float*)d_ws;                    // N*64 floats = 2.56 MB

    // 1) init output (energy bias + zeros for force accumulation)
    {
        int blocks = (out_size + 255) / 256;
        init_out_kernel<<<blocks, 256, 0, stream>>>(out, b_last, out_size);
    }

    // 2) per-atom table + energy
    {
        int total  = N_ATOMS * N_DESC;              // 640000
        int blocks = total / 256;                   // 2500
        atom_kernel<<<blocks, 256, 0, stream>>>(coeffs, w1, b1, w_last, g, out);
    }

    // 3) per-pair force + scatter
    {
        int waves_per_block = 256 / 64;             // 4
        int blocks = (N_PAIRS + waves_per_block - 1) / waves_per_block; // 125000
        pair_kernel<<<blocks, 256, 0, stream>>>(cd, g, central, neigh, out + 1);
    }
}

// Round 2
// 546.652 us; speedup vs baseline: 1.1292x; 1.1292x over previous
//
#include <hip/hip_runtime.h>

#define N_ATOMS 10000
#define N_PAIRS 500000
#define N_DESC  64

// ---------------------------------------------------------------------------
// Kernel 0: initialize output. d_out[0] = b_last (energy bias), rest = 0.
// Harness re-poisons d_out to 0xAA before every timed launch.
// ---------------------------------------------------------------------------
__global__ void init_out_kernel(float* __restrict__ out,
                                const float* __restrict__ b_last,
                                int out_size) {
    int i = blockIdx.x * blockDim.x + threadIdx.x;
    if (i < out_size) out[i] = (i == 0) ? b_last[0] : 0.0f;
}

// ---------------------------------------------------------------------------
// Kernel A: per-atom table + energy reduction.
//   e       = tanh(coeffs[n][d] * w1[d] + b1[d])
//   g[n][d] = (1 - e*e) * w1[d] * w_last[d]      (stored to workspace)
//   energy += e * w_last[d] / N_ATOMS            (atomic into out[0])
// ---------------------------------------------------------------------------
__global__ void atom_kernel(const float* __restrict__ coeffs,
                            const float* __restrict__ w1,
                            const float* __restrict__ b1,
                            const float* __restrict__ w_last,
                            float* __restrict__ g,
                            float* __restrict__ out) {
    const int i = blockIdx.x * blockDim.x + threadIdx.x;   // < N_ATOMS*N_DESC
    const int d = i & (N_DESC - 1);

    const float wd = w1[d];
    const float wl = w_last[d];
    const float e  = tanhf(coeffs[i] * wd + b1[d]);

    g[i] = (1.0f - e * e) * wd * wl;

    float epart = e * wl * (1.0f / (float)N_ATOMS);

    #pragma unroll
    for (int off = 32; off > 0; off >>= 1)
        epart += __shfl_down(epart, off, 64);

    __shared__ float smem[4];                 // 256 threads = 4 waves
    const int lane = threadIdx.x & 63;
    const int wv   = threadIdx.x >> 6;
    if (lane == 0) smem[wv] = epart;
    __syncthreads();
    if (threadIdx.x == 0) {
        atomicAdd(out, smem[0] + smem[1] + smem[2] + smem[3]);
    }
}

// ---------------------------------------------------------------------------
// Kernel B: 16 lanes per pair, float4 (16B) loads — each pair row (64 floats
// = 256B) is read by 16 lanes as global_load_dwordx4. One wave handles 4
// pairs; xor-shuffle masks 1/2/4/8 reduce within each 16-lane group without
// crossing pair boundaries. 3 shuffles/pair instead of 18.
//   s_k = sum_d g[central[p]][d] * cd[k][p][d]      (k = 0,1,2)
//   out_f[k][neigh[p]] += -s_k
// ---------------------------------------------------------------------------
__global__ void __launch_bounds__(256)
pair_kernel(const float4* __restrict__ cd4,     // [3, P, 16] float4
            const float4* __restrict__ g4,      // [N, 16] float4
            const int*   __restrict__ central,  // [P]
            const int*   __restrict__ neigh,    // [P]
            float* __restrict__ out_f) {        // [3, N] (= d_out+1)
    const int tid = blockIdx.x * blockDim.x + threadIdx.x;
    const int p   = tid >> 4;                   // pair index
    const int l   = tid & 15;                   // lane within pair group
    if (p >= N_PAIRS) return;

    const int c = central[p];
    const float4 gv = g4[c * 16 + l];

    const size_t plane4 = (size_t)N_PAIRS * 16;
    const float4* base = cd4 + (size_t)p * 16 + l;
    const float4 b0 = base[0];
    const float4 b1v = base[plane4];
    const float4 b2 = base[2 * plane4];

    float s0 = gv.x * b0.x  + gv.y * b0.y  + gv.z * b0.z  + gv.w * b0.w;
    float s1 = gv.x * b1v.x + gv.y * b1v.y + gv.z * b1v.z + gv.w * b1v.w;
    float s2 = gv.x * b2.x  + gv.y * b2.y  + gv.z * b2.z  + gv.w * b2.w;

    #pragma unroll
    for (int m = 8; m > 0; m >>= 1) {
        s0 += __shfl_xor(s0, m, 64);
        s1 += __shfl_xor(s1, m, 64);
        s2 += __shfl_xor(s2, m, 64);
    }

    if (l == 0) {
        const int nb = neigh[p];
        atomicAdd(&out_f[nb],               -s0);
        atomicAdd(&out_f[N_ATOMS + nb],     -s1);
        atomicAdd(&out_f[2 * N_ATOMS + nb], -s2);
    }
}

// ---------------------------------------------------------------------------
// Launch
// ---------------------------------------------------------------------------
extern "C" void kernel_launch(void* const* d_in, const int* in_sizes, int n_in,
                              void* d_out, int out_size, void* d_ws, size_t ws_size,
                              hipStream_t stream) {
    const float* coeffs  = (const float*)d_in[0];   // [1, N, 64]
    const float* cd      = (const float*)d_in[1];   // [1, 3, P, 64]
    const float* w1      = (const float*)d_in[2];   // [64]
    const float* b1      = (const float*)d_in[3];   // [64]
    const float* w_last  = (const float*)d_in[4];   // [64]
    const float* b_last  = (const float*)d_in[5];   // [1]
    const int*   central = (const int*)d_in[6];     // [P]
    const int*   neigh   = (const int*)d_in[7];     // [P]

    float* out = (float*)d_out;                     // [0]=energy, [1..30000]=forces
    float* g   = (float*)d_ws;                      // N*64 floats = 2.56 MB

    // 1) init output (energy bias + zeros for force accumulation)
    {
        int blocks = (out_size + 255) / 256;
        init_out_kernel<<<blocks, 256, 0, stream>>>(out, b_last, out_size);
    }

    // 2) per-atom table + energy
    {
        int total  = N_ATOMS * N_DESC;              // 640000
        int blocks = total / 256;                   // 2500
        atom_kernel<<<blocks, 256, 0, stream>>>(coeffs, w1, b1, w_last, g, out);
    }

    // 3) per-pair force + scatter: 16 threads per pair
    {
        long long total_threads = (long long)N_PAIRS * 16;   // 8M
        int blocks = (int)((total_threads + 255) / 256);     // 31250
        pair_kernel<<<blocks, 256, 0, stream>>>(
            (const float4*)cd, (const float4*)g, central, neigh, out + 1);
    }
}

// Round 4
// 510.457 us; speedup vs baseline: 1.2093x; 1.0709x over previous
//
#include <hip/hip_runtime.h>

#define N_ATOMS 10000
#define N_PAIRS 500000
#define N_DESC  64
#define HALF_PAIRS (N_PAIRS / 2)
#define ATOM_BLOCKS (N_ATOMS * N_DESC / 256)   // 2500
#define FORCE_ELEMS (3 * N_ATOMS)              // 30000

// ws layout: [0 .. N*64)              g table (2.56 MB)
//            [N*64 .. N*64+2500)      per-block energy partials
#define WS_EPART_OFF (N_ATOMS * N_DESC)

// native 4-float vector (usable with __builtin_nontemporal_load, unlike
// HIP_vector_type float4)
typedef float f4 __attribute__((ext_vector_type(4)));

// ---------------------------------------------------------------------------
// Kernel A: per-atom table + per-block energy partials + force-output zeroing.
//   e       = tanh(coeffs[n][d] * w1[d] + b1[d])
//   g[n][d] = (1 - e*e) * w1[d] * w_last[d]
//   epart_block = sum(e * w_last / N_ATOMS)   (plain store, no atomics)
// Blocks 0..117 additionally zero out[1..30000] (force accumulators).
// out[0] (energy) is written solely by pair_kernel block 0 — no race.
// ---------------------------------------------------------------------------
__global__ void __launch_bounds__(256)
atom_kernel(const float* __restrict__ coeffs,
            const float* __restrict__ w1,
            const float* __restrict__ b1,
            const float* __restrict__ w_last,
            float* __restrict__ ws,
            float* __restrict__ out) {
    // zero the force-accumulator region of d_out (poisoned 0xAA by harness)
    if (blockIdx.x < 118) {
        int j = blockIdx.x * 256 + threadIdx.x;
        if (j < FORCE_ELEMS) out[1 + j] = 0.0f;
    }

    const int i = blockIdx.x * blockDim.x + threadIdx.x;   // < N_ATOMS*N_DESC
    const int d = i & (N_DESC - 1);

    const float wd = w1[d];
    const float wl = w_last[d];
    const float e  = tanhf(coeffs[i] * wd + b1[d]);

    ws[i] = (1.0f - e * e) * wd * wl;

    float epart = e * wl * (1.0f / (float)N_ATOMS);
    #pragma unroll
    for (int off = 32; off > 0; off >>= 1)
        epart += __shfl_down(epart, off, 64);

    __shared__ float smem[4];
    const int lane = threadIdx.x & 63;
    const int wv   = threadIdx.x >> 6;
    if (lane == 0) smem[wv] = epart;
    __syncthreads();
    if (threadIdx.x == 0)
        ws[WS_EPART_OFF + blockIdx.x] = smem[0] + smem[1] + smem[2] + smem[3];
}

// ---------------------------------------------------------------------------
// Kernel B: 16 lanes per pair-slot, TWO pairs per slot (p and p+HALF_PAIRS)
// for 2x memory-level parallelism. All 8 dwordx4 loads issue before any use.
// cd loads are non-temporal (zero reuse) so the 2.56 MB g table stays in L2.
// Block 0 wave 0 additionally reduces the 2500 energy partials into out[0].
// ---------------------------------------------------------------------------
__global__ void __launch_bounds__(256)
pair_kernel(const f4* __restrict__ cd4,         // [3, P, 16] f4
            const f4* __restrict__ g4,          // [N, 16] f4
            const float*  __restrict__ ws,      // energy partials at WS_EPART_OFF
            const float*  __restrict__ b_last,
            const int*    __restrict__ central, // [P]
            const int*    __restrict__ neigh,   // [P]
            float* __restrict__ out) {          // [0]=energy, [1..]=forces [3,N]
    // --- energy finalize (block 0, wave 0) ---
    if (blockIdx.x == 0 && threadIdx.x < 64) {
        float s = 0.0f;
        for (int idx = threadIdx.x; idx < ATOM_BLOCKS; idx += 64)
            s += ws[WS_EPART_OFF + idx];
        #pragma unroll
        for (int off = 32; off > 0; off >>= 1)
            s += __shfl_down(s, off, 64);
        if (threadIdx.x == 0) out[0] = s + b_last[0];
    }

    float* __restrict__ out_f = out + 1;        // [3, N_ATOMS]

    const int tid = blockIdx.x * blockDim.x + threadIdx.x;
    const int grp = tid >> 4;                   // pair-slot index < HALF_PAIRS
    const int l   = tid & 15;
    if (grp >= HALF_PAIRS) return;

    const int pA = grp;
    const int pB = grp + HALF_PAIRS;

    const int cA = central[pA];
    const int cB = central[pB];
    const int nA = neigh[pA];
    const int nB = neigh[pB];

    const size_t plane4 = (size_t)N_PAIRS * 16;
    const f4* baseA = cd4 + (size_t)pA * 16 + l;
    const f4* baseB = cd4 + (size_t)pB * 16 + l;

    // issue all 6 stream loads + 2 gathers up front
    const f4 a0 = __builtin_nontemporal_load(baseA);
    const f4 a1 = __builtin_nontemporal_load(baseA + plane4);
    const f4 a2 = __builtin_nontemporal_load(baseA + 2 * plane4);
    const f4 c0 = __builtin_nontemporal_load(baseB);
    const f4 c1 = __builtin_nontemporal_load(baseB + plane4);
    const f4 c2 = __builtin_nontemporal_load(baseB + 2 * plane4);
    const f4 gA = g4[cA * 16 + l];
    const f4 gB = g4[cB * 16 + l];

    float sA0 = gA.x * a0.x + gA.y * a0.y + gA.z * a0.z + gA.w * a0.w;
    float sA1 = gA.x * a1.x + gA.y * a1.y + gA.z * a1.z + gA.w * a1.w;
    float sA2 = gA.x * a2.x + gA.y * a2.y + gA.z * a2.z + gA.w * a2.w;
    float sB0 = gB.x * c0.x + gB.y * c0.y + gB.z * c0.z + gB.w * c0.w;
    float sB1 = gB.x * c1.x + gB.y * c1.y + gB.z * c1.z + gB.w * c1.w;
    float sB2 = gB.x * c2.x + gB.y * c2.y + gB.z * c2.z + gB.w * c2.w;

    #pragma unroll
    for (int m = 8; m > 0; m >>= 1) {
        sA0 += __shfl_xor(sA0, m, 64);
        sA1 += __shfl_xor(sA1, m, 64);
        sA2 += __shfl_xor(sA2, m, 64);
        sB0 += __shfl_xor(sB0, m, 64);
        sB1 += __shfl_xor(sB1, m, 64);
        sB2 += __shfl_xor(sB2, m, 64);
    }

    // after xor-reduction every lane in the 16-group holds the full sums;
    // spread the 6 atomics across lanes 0,4,8 -> 2 atomic instrs per wave
    if (l == 0) {
        atomicAdd(&out_f[nA], -sA0);
        atomicAdd(&out_f[nB], -sB0);
    } else if (l == 4) {
        atomicAdd(&out_f[N_ATOMS + nA], -sA1);
        atomicAdd(&out_f[N_ATOMS + nB], -sB1);
    } else if (l == 8) {
        atomicAdd(&out_f[2 * N_ATOMS + nA], -sA2);
        atomicAdd(&out_f[2 * N_ATOMS + nB], -sB2);
    }
}

// ---------------------------------------------------------------------------
// Launch — two dispatches total.
// ---------------------------------------------------------------------------
extern "C" void kernel_launch(void* const* d_in, const int* in_sizes, int n_in,
                              void* d_out, int out_size, void* d_ws, size_t ws_size,
                              hipStream_t stream) {
    const float* coeffs  = (const float*)d_in[0];   // [1, N, 64]
    const float* cd      = (const float*)d_in[1];   // [1, 3, P, 64]
    const float* w1      = (const float*)d_in[2];   // [64]
    const float* b1      = (const float*)d_in[3];   // [64]
    const float* w_last  = (const float*)d_in[4];   // [64]
    const float* b_last  = (const float*)d_in[5];   // [1]
    const int*   central = (const int*)d_in[6];     // [P]
    const int*   neigh   = (const int*)d_in[7];     // [P]

    float* out = (float*)d_out;
    float* ws  = (float*)d_ws;

    // 1) per-atom table + energy partials + force-output zeroing
    atom_kernel<<<ATOM_BLOCKS, 256, 0, stream>>>(coeffs, w1, b1, w_last, ws, out);

    // 2) per-pair force + scatter (+ energy finalize in block 0)
    {
        long long total_threads = (long long)HALF_PAIRS * 16;    // 4M
        int blocks = (int)((total_threads + 255) / 256);         // 15625
        pair_kernel<<<blocks, 256, 0, stream>>>(
            (const f4*)cd, (const f4*)ws, ws, b_last, central, neigh, out);
    }
}